// Round 3
// baseline (1083.906 us; speedup 1.0000x reference)
//
#include <hip/hip_runtime.h>
#include <hip/hip_bf16.h>

#define LN_EPS 1e-5f

// ---------------- CSR build ----------------

__global__ __launch_bounds__(256) void hist_kernel(
    const int* __restrict__ ei, int* __restrict__ deg, int E)
{
    int e = blockIdx.x * 256 + threadIdx.x;
    if (e < E) atomicAdd(&deg[ei[E + e]], 1);
}

__global__ __launch_bounds__(256) void scan1_kernel(
    const int* __restrict__ deg, int* __restrict__ rowstart,
    int* __restrict__ tilesum, int n)
{
    __shared__ int wsum[4];
    int t = threadIdx.x;
    int base = blockIdx.x * 2048 + t * 8;
    int v[8]; int tsum = 0;
    #pragma unroll
    for (int i = 0; i < 8; ++i) { v[i] = (base + i < n) ? deg[base + i] : 0; tsum += v[i]; }
    int lane = t & 63, w = t >> 6;
    int sc = tsum;
    #pragma unroll
    for (int off = 1; off < 64; off <<= 1) {
        int y = __shfl_up(sc, off);
        if (lane >= off) sc += y;
    }
    if (lane == 63) wsum[w] = sc;
    __syncthreads();
    int woff = 0;
    for (int j = 0; j < w; ++j) woff += wsum[j];
    int run = woff + sc - tsum;
    #pragma unroll
    for (int i = 0; i < 8; ++i) { if (base + i < n) rowstart[base + i] = run; run += v[i]; }
    if (t == 255) tilesum[blockIdx.x] = wsum[0] + wsum[1] + wsum[2] + wsum[3];
}

__global__ void scan2_kernel(int* tilesum, int T)
{
    if (blockIdx.x == 0 && threadIdx.x == 0) {
        int run = 0;
        for (int i = 0; i < T; ++i) { int v = tilesum[i]; tilesum[i] = run; run += v; }
    }
}

__global__ __launch_bounds__(256) void scan3_kernel(
    int* __restrict__ rowstart, const int* __restrict__ tilesum, int n, int E)
{
    int i = blockIdx.x * 256 + threadIdx.x;
    if (i < n) rowstart[i] += tilesum[i >> 11];
    if (i == 0) rowstart[n] = E;
}

__global__ __launch_bounds__(256) void fill_kernel(
    const int* __restrict__ ei, const int* __restrict__ rowstart,
    int* __restrict__ cursor, int* __restrict__ esrc, int E)
{
    int e = blockIdx.x * 256 + threadIdx.x;
    if (e < E) {
        int dst = ei[E + e];
        int pos = rowstart[dst] + atomicAdd(&cursor[dst], 1);
        esrc[pos] = ei[e];
    }
}

// ---------------- gather: CSR mean-aggregate ----------------
// Block 256 = 4 waves, one node per wave. Wave = 4 edge-groups x 16 lanes;
// lane-in-group owns a float4 of the row (16 lanes x 16B = 256B coalesced).
// 4 (unroll 8) independent row loads in flight per wave; no LDS, low VGPR ->
// full occupancy to hide L2/L3 latency. Writes divided mean into `mean`.
__global__ __launch_bounds__(256) void gather_kernel(
    const float* __restrict__ x,
    const int*   __restrict__ rowstart,
    const int*   __restrict__ esrc,
    float* __restrict__ mean,
    int N)
{
    int tid  = threadIdx.x;
    int lane = tid & 63;
    int g    = lane >> 4;        // edge group 0..3
    int l4   = (lane & 15) * 4;  // float4 slot
    int node = blockIdx.x * 4 + (tid >> 6);
    if (node >= N) return;
    int s0 = rowstart[node], s1 = rowstart[node + 1];

    float4 a0 = make_float4(0.f, 0.f, 0.f, 0.f);
    float4 a1 = make_float4(0.f, 0.f, 0.f, 0.f);
    int e = s0 + g;
    for (; e + 4 < s1; e += 8) {
        int sA = esrc[e];
        int sB = esrc[e + 4];
        float4 va = *(const float4*)&x[(size_t)sA * 64 + l4];
        float4 vb = *(const float4*)&x[(size_t)sB * 64 + l4];
        a0.x += va.x; a0.y += va.y; a0.z += va.z; a0.w += va.w;
        a1.x += vb.x; a1.y += vb.y; a1.z += vb.z; a1.w += vb.w;
    }
    if (e < s1) {
        float4 va = *(const float4*)&x[(size_t)esrc[e] * 64 + l4];
        a0.x += va.x; a0.y += va.y; a0.z += va.z; a0.w += va.w;
    }
    a0.x += a1.x; a0.y += a1.y; a0.z += a1.z; a0.w += a1.w;

    // reduce the 4 groups (lanes l, l+16, l+32, l+48)
    a0.x += __shfl_xor(a0.x, 32); a0.y += __shfl_xor(a0.y, 32);
    a0.z += __shfl_xor(a0.z, 32); a0.w += __shfl_xor(a0.w, 32);
    a0.x += __shfl_xor(a0.x, 16); a0.y += __shfl_xor(a0.y, 16);
    a0.z += __shfl_xor(a0.z, 16); a0.w += __shfl_xor(a0.w, 16);

    if (g == 0) {
        float inv = 1.0f / fmaxf((float)(s1 - s0), 1.0f);
        float4 r = make_float4(a0.x * inv, a0.y * inv, a0.z * inv, a0.w * inv);
        *(float4*)&mean[(size_t)node * 64 + l4] = r;
    }
}

// ---------------- MLP + LayerNorm + ELU ----------------
// Block 512 = 8 waves, NPW=4 nodes per wave. Weights transposed in LDS
// (sWT[d][j], +1 pad -> 2-way free). Rows staged in LDS, read back as
// uniform-address float4 broadcasts (free).
#define NPW 4

__global__ __launch_bounds__(512) void mlp_kernel(
    const float* __restrict__ x,
    const float* __restrict__ mean,   // aliases d_out; each wave reads its own
                                      // rows before overwriting them
    const float* __restrict__ Wl,
    const float* __restrict__ Wr,
    const float* __restrict__ bias,
    const float* __restrict__ gamma,
    const float* __restrict__ beta,
    float* __restrict__ out,
    int N)
{
    __shared__ float sWlT[64][65];
    __shared__ float sWrT[64][65];
    __shared__ float sm[32][68];
    __shared__ float sx[32][68];

    int tid  = threadIdx.x;
    int lane = tid & 63;
    int w    = tid >> 6;

    for (int i = tid; i < 64 * 64; i += 512) {
        int j = i >> 6, d = i & 63;
        sWlT[d][j] = Wl[i];
        sWrT[d][j] = Wr[i];
    }
    __syncthreads();

    int nbase = blockIdx.x * 32 + w * NPW;
    int rows  = w * NPW;

    #pragma unroll
    for (int n = 0; n < NPW; ++n) {
        int node = nbase + n;
        if (node < N) {
            sm[rows + n][lane] = mean[(size_t)node * 64 + lane];
            sx[rows + n][lane] = x[(size_t)node * 64 + lane];
        }
    }
    // same-wave LDS write->read; compiler inserts lgkmcnt wait

    float bj = bias[lane];
    float acc[NPW];
    #pragma unroll
    for (int n = 0; n < NPW; ++n) acc[n] = bj;

    #pragma unroll
    for (int c = 0; c < 16; ++c) {
        int d0 = c * 4;
        float wl0 = sWlT[d0 + 0][lane], wl1 = sWlT[d0 + 1][lane];
        float wl2 = sWlT[d0 + 2][lane], wl3 = sWlT[d0 + 3][lane];
        float wr0 = sWrT[d0 + 0][lane], wr1 = sWrT[d0 + 1][lane];
        float wr2 = sWrT[d0 + 2][lane], wr3 = sWrT[d0 + 3][lane];
        #pragma unroll
        for (int n = 0; n < NPW; ++n) {
            float4 mb = *(const float4*)&sm[rows + n][d0];
            float4 xb = *(const float4*)&sx[rows + n][d0];
            acc[n] += mb.x * wl0 + mb.y * wl1 + mb.z * wl2 + mb.w * wl3
                    + xb.x * wr0 + xb.y * wr1 + xb.z * wr2 + xb.w * wr3;
        }
    }

    float g  = gamma[lane];
    float bt = beta[lane];
    #pragma unroll
    for (int n = 0; n < NPW; ++n) {
        int node = nbase + n;
        if (node >= N) break;
        float h = acc[n];
        float s = h, s2 = h * h;
        #pragma unroll
        for (int off = 32; off >= 1; off >>= 1) {
            s  += __shfl_xor(s,  off);
            s2 += __shfl_xor(s2, off);
        }
        float mu  = s * (1.0f / 64.0f);
        float var = s2 * (1.0f / 64.0f) - mu * mu;
        float hn  = (h - mu) * rsqrtf(var + LN_EPS) * g + bt;
        out[(size_t)node * 64 + lane] = hn > 0.0f ? hn : expm1f(hn);
    }
}

extern "C" void kernel_launch(void* const* d_in, const int* in_sizes, int n_in,
                              void* d_out, int out_size, void* d_ws, size_t ws_size,
                              hipStream_t stream) {
    const float* x     = (const float*)d_in[0];
    const int*   ei    = (const int*)  d_in[1];
    const float* Wl    = (const float*)d_in[2];
    const float* Wr    = (const float*)d_in[3];
    const float* bias  = (const float*)d_in[4];
    const float* gamma = (const float*)d_in[5];
    const float* beta  = (const float*)d_in[6];

    int N = in_sizes[0] / 64;
    int E = in_sizes[1] / 2;

    int* deg      = (int*)d_ws;            // N
    int* cursor   = deg + N;               // N
    int* rowstart = cursor + N;            // N+1
    int* tilesum  = rowstart + (N + 1);    // <=64
    int* esrc     = tilesum + 64;          // E
    float* mean   = (float*)d_out;         // N*64, overwritten in place by mlp

    hipMemsetAsync(deg, 0, (size_t)2 * N * sizeof(int), stream);

    int eblocks = (E + 255) / 256;
    hist_kernel<<<eblocks, 256, 0, stream>>>(ei, deg, E);

    int T = (N + 2047) / 2048;
    scan1_kernel<<<T, 256, 0, stream>>>(deg, rowstart, tilesum, N);
    scan2_kernel<<<1, 64, 0, stream>>>(tilesum, T);
    scan3_kernel<<<(N + 255) / 256, 256, 0, stream>>>(rowstart, tilesum, N, E);

    fill_kernel<<<eblocks, 256, 0, stream>>>(ei, rowstart, cursor, esrc, E);

    gather_kernel<<<(N + 3) / 4, 256, 0, stream>>>(x, rowstart, esrc, mean, N);

    mlp_kernel<<<(N + 31) / 32, 512, 0, stream>>>(x, mean, Wl, Wr, bias, gamma, beta,
                                                  (float*)d_out, N);
}

// Round 4
// 274.035 us; speedup vs baseline: 3.9554x; 3.9554x over previous
//
#include <hip/hip_runtime.h>
#include <hip/hip_bf16.h>

#define LN_EPS 1e-5f

// ---------------- CSR build ----------------

__global__ __launch_bounds__(256) void hist_kernel(
    const int* __restrict__ ei, int* __restrict__ deg, int E)
{
    int e = blockIdx.x * 256 + threadIdx.x;
    if (e < E) atomicAdd(&deg[ei[E + e]], 1);
}

__global__ __launch_bounds__(256) void scan1_kernel(
    const int* __restrict__ deg, int* __restrict__ rowstart,
    int* __restrict__ tilesum, int n)
{
    __shared__ int wsum[4];
    int t = threadIdx.x;
    int base = blockIdx.x * 2048 + t * 8;
    int v[8]; int tsum = 0;
    #pragma unroll
    for (int i = 0; i < 8; ++i) { v[i] = (base + i < n) ? deg[base + i] : 0; tsum += v[i]; }
    int lane = t & 63, w = t >> 6;
    int sc = tsum;
    #pragma unroll
    for (int off = 1; off < 64; off <<= 1) {
        int y = __shfl_up(sc, off);
        if (lane >= off) sc += y;
    }
    if (lane == 63) wsum[w] = sc;
    __syncthreads();
    int woff = 0;
    for (int j = 0; j < w; ++j) woff += wsum[j];
    int run = woff + sc - tsum;
    #pragma unroll
    for (int i = 0; i < 8; ++i) { if (base + i < n) rowstart[base + i] = run; run += v[i]; }
    if (t == 255) tilesum[blockIdx.x] = wsum[0] + wsum[1] + wsum[2] + wsum[3];
}

__global__ void scan2_kernel(int* tilesum, int T)
{
    if (blockIdx.x == 0 && threadIdx.x == 0) {
        int run = 0;
        for (int i = 0; i < T; ++i) { int v = tilesum[i]; tilesum[i] = run; run += v; }
    }
}

__global__ __launch_bounds__(256) void scan3_kernel(
    int* __restrict__ rowstart, const int* __restrict__ tilesum, int n, int E)
{
    int i = blockIdx.x * 256 + threadIdx.x;
    if (i < n) rowstart[i] += tilesum[i >> 11];
    if (i == 0) rowstart[n] = E;
}

__global__ __launch_bounds__(256) void fill_kernel(
    const int* __restrict__ ei, const int* __restrict__ rowstart,
    int* __restrict__ cursor, int* __restrict__ esrc, int E)
{
    int e = blockIdx.x * 256 + threadIdx.x;
    if (e < E) {
        int dst = ei[E + e];
        int pos = rowstart[dst] + atomicAdd(&cursor[dst], 1);
        esrc[pos] = ei[e];
    }
}

// ---------------- fused gather + SAGE + LN + ELU (register-only) ----------------
// One node per wave, grid-stride. Lane j holds weight ROWS Wl[j][*], Wr[j][*]
// in 128 VGPRs (loaded once per wave, amortized over ~16 nodes). No LDS.
// Gather: lane = feature d; edge ids staged 64-wide in a VGPR, broadcast
// per-edge via v_readlane (SGPR) -> uniform-base + lane*4 coalesced loads.
// MLP: fully-unrolled d loop; readlane(mv,d)/readlane(xv,d) feed v_fmac as
// the single allowed SGPR operand. All arrays unroll-constant indexed -> no
// scratch (rule: runtime-indexed per-thread arrays spill to local memory).
__global__ __launch_bounds__(256, 2) void fused_kernel(
    const float* __restrict__ x,
    const int*   __restrict__ rowstart,
    const int*   __restrict__ esrc,
    const float* __restrict__ Wl,
    const float* __restrict__ Wr,
    const float* __restrict__ bias,
    const float* __restrict__ gamma,
    const float* __restrict__ beta,
    float* __restrict__ out,
    int N, int nwaves)
{
    int lane = threadIdx.x & 63;
    int gwid = (blockIdx.x * 256 + threadIdx.x) >> 6;
    if (gwid >= N) return;   // wave-uniform

    float wl[64], wr[64];
    {
        const float* pl = Wl + lane * 64;
        const float* pr = Wr + lane * 64;
        #pragma unroll
        for (int t = 0; t < 16; ++t) {
            float4 a = *(const float4*)(pl + t * 4);
            float4 b = *(const float4*)(pr + t * 4);
            wl[t*4+0] = a.x; wl[t*4+1] = a.y; wl[t*4+2] = a.z; wl[t*4+3] = a.w;
            wr[t*4+0] = b.x; wr[t*4+1] = b.y; wr[t*4+2] = b.z; wr[t*4+3] = b.w;
        }
    }
    float bj  = bias[lane];
    float gj  = gamma[lane];
    float btj = beta[lane];

    for (int node = gwid; node < N; node += nwaves) {
        int s0 = rowstart[node], s1 = rowstart[node + 1];

        float m0 = 0.f, m1 = 0.f, m2 = 0.f, m3 = 0.f;
        for (int be = s0; be < s1; be += 64) {
            int ee = be + lane;
            int ev = (ee < s1) ? esrc[ee] : 0;   // coalesced 64-wide stage
            int m  = s1 - be; if (m > 64) m = 64;
            int k  = 0;
            for (; k + 4 <= m; k += 4) {
                int a0 = __builtin_amdgcn_readlane(ev, k + 0);
                int a1 = __builtin_amdgcn_readlane(ev, k + 1);
                int a2 = __builtin_amdgcn_readlane(ev, k + 2);
                int a3 = __builtin_amdgcn_readlane(ev, k + 3);
                m0 += x[(size_t)a0 * 64 + lane];
                m1 += x[(size_t)a1 * 64 + lane];
                m2 += x[(size_t)a2 * 64 + lane];
                m3 += x[(size_t)a3 * 64 + lane];
            }
            for (; k < m; ++k) {
                int a0 = __builtin_amdgcn_readlane(ev, k);
                m0 += x[(size_t)a0 * 64 + lane];
            }
        }
        float mv = ((m0 + m1) + (m2 + m3)) / fmaxf((float)(s1 - s0), 1.0f);
        float xv = x[(size_t)node * 64 + lane];

        float acc = bj;
        #pragma unroll
        for (int d = 0; d < 64; ++d) {
            float md = __int_as_float(__builtin_amdgcn_readlane(__float_as_int(mv), d));
            float xd = __int_as_float(__builtin_amdgcn_readlane(__float_as_int(xv), d));
            acc += md * wl[d] + xd * wr[d];
        }

        float s = acc, s2 = acc * acc;
        #pragma unroll
        for (int off = 32; off >= 1; off >>= 1) {
            s  += __shfl_xor(s,  off);
            s2 += __shfl_xor(s2, off);
        }
        float mu  = s * (1.0f / 64.0f);
        float var = s2 * (1.0f / 64.0f) - mu * mu;
        float hn  = (acc - mu) * rsqrtf(var + LN_EPS) * gj + btj;
        out[(size_t)node * 64 + lane] = hn > 0.0f ? hn : expm1f(hn);
    }
}

extern "C" void kernel_launch(void* const* d_in, const int* in_sizes, int n_in,
                              void* d_out, int out_size, void* d_ws, size_t ws_size,
                              hipStream_t stream) {
    const float* x     = (const float*)d_in[0];
    const int*   ei    = (const int*)  d_in[1];
    const float* Wl    = (const float*)d_in[2];
    const float* Wr    = (const float*)d_in[3];
    const float* bias  = (const float*)d_in[4];
    const float* gamma = (const float*)d_in[5];
    const float* beta  = (const float*)d_in[6];

    int N = in_sizes[0] / 64;
    int E = in_sizes[1] / 2;

    int* deg      = (int*)d_ws;            // N
    int* cursor   = deg + N;               // N
    int* rowstart = cursor + N;            // N+1
    int* tilesum  = rowstart + (N + 1);    // <=64
    int* esrc     = tilesum + 64;          // E

    hipMemsetAsync(deg, 0, (size_t)2 * N * sizeof(int), stream);

    int eblocks = (E + 255) / 256;
    hist_kernel<<<eblocks, 256, 0, stream>>>(ei, deg, E);

    int T = (N + 2047) / 2048;
    scan1_kernel<<<T, 256, 0, stream>>>(deg, rowstart, tilesum, N);
    scan2_kernel<<<1, 64, 0, stream>>>(tilesum, T);
    scan3_kernel<<<(N + 255) / 256, 256, 0, stream>>>(rowstart, tilesum, N, E);

    fill_kernel<<<eblocks, 256, 0, stream>>>(ei, rowstart, cursor, esrc, E);

    int blocks = 1536;                     // 6144 waves, ~16 nodes each
    int nwaves = blocks * 4;
    fused_kernel<<<blocks, 256, 0, stream>>>(x, rowstart, esrc, Wl, Wr,
                                             bias, gamma, beta, (float*)d_out,
                                             N, nwaves);
}

// Round 5
// 271.558 us; speedup vs baseline: 3.9914x; 1.0091x over previous
//
#include <hip/hip_runtime.h>
#include <hip/hip_bf16.h>

#define LN_EPS 1e-5f

// ---------------- CSR build ----------------

__global__ __launch_bounds__(256) void hist_kernel(
    const int* __restrict__ ei, int* __restrict__ deg, int E)
{
    int e = blockIdx.x * 256 + threadIdx.x;
    if (e < E) atomicAdd(&deg[ei[E + e]], 1);
}

__global__ __launch_bounds__(256) void scan1_kernel(
    const int* __restrict__ deg, int* __restrict__ rowstart,
    int* __restrict__ tilesum, int n)
{
    __shared__ int wsum[4];
    int t = threadIdx.x;
    int base = blockIdx.x * 2048 + t * 8;
    int v[8]; int tsum = 0;
    #pragma unroll
    for (int i = 0; i < 8; ++i) { v[i] = (base + i < n) ? deg[base + i] : 0; tsum += v[i]; }
    int lane = t & 63, w = t >> 6;
    int sc = tsum;
    #pragma unroll
    for (int off = 1; off < 64; off <<= 1) {
        int y = __shfl_up(sc, off);
        if (lane >= off) sc += y;
    }
    if (lane == 63) wsum[w] = sc;
    __syncthreads();
    int woff = 0;
    for (int j = 0; j < w; ++j) woff += wsum[j];
    int run = woff + sc - tsum;
    #pragma unroll
    for (int i = 0; i < 8; ++i) { if (base + i < n) rowstart[base + i] = run; run += v[i]; }
    if (t == 255) tilesum[blockIdx.x] = wsum[0] + wsum[1] + wsum[2] + wsum[3];
}

__global__ void scan2_kernel(int* tilesum, int T)
{
    if (blockIdx.x == 0 && threadIdx.x == 0) {
        int run = 0;
        for (int i = 0; i < T; ++i) { int v = tilesum[i]; tilesum[i] = run; run += v; }
    }
}

__global__ __launch_bounds__(256) void scan3_kernel(
    int* __restrict__ rowstart, const int* __restrict__ tilesum, int n, int E)
{
    int i = blockIdx.x * 256 + threadIdx.x;
    if (i < n) rowstart[i] += tilesum[i >> 11];
    if (i == 0) rowstart[n] = E;
}

__global__ __launch_bounds__(256) void fill_kernel(
    const int* __restrict__ ei, const int* __restrict__ rowstart,
    int* __restrict__ cursor, int* __restrict__ esrc, int E)
{
    int e = blockIdx.x * 256 + threadIdx.x;
    if (e < E) {
        int dst = ei[E + e];
        int pos = rowstart[dst] + atomicAdd(&cursor[dst], 1);
        esrc[pos] = ei[e];
    }
}

// ---------------- gather: CSR mean-aggregate (round-3 proven) ----------------
// One node per wave; wave = 4 edge-groups x 16 lanes x float4 (256B/row).
// 8 loads in flight per wave, 100k-wave TLP hides latency. No LDS, low VGPR.
__global__ __launch_bounds__(256) void gather_kernel(
    const float* __restrict__ x,
    const int*   __restrict__ rowstart,
    const int*   __restrict__ esrc,
    float* __restrict__ mean,
    int N)
{
    int tid  = threadIdx.x;
    int lane = tid & 63;
    int g    = lane >> 4;
    int l4   = (lane & 15) * 4;
    int node = blockIdx.x * 4 + (tid >> 6);
    if (node >= N) return;
    int s0 = rowstart[node], s1 = rowstart[node + 1];

    float4 a0 = make_float4(0.f, 0.f, 0.f, 0.f);
    float4 a1 = make_float4(0.f, 0.f, 0.f, 0.f);
    int e = s0 + g;
    for (; e + 4 < s1; e += 8) {
        int sA = esrc[e];
        int sB = esrc[e + 4];
        float4 va = *(const float4*)&x[(size_t)sA * 64 + l4];
        float4 vb = *(const float4*)&x[(size_t)sB * 64 + l4];
        a0.x += va.x; a0.y += va.y; a0.z += va.z; a0.w += va.w;
        a1.x += vb.x; a1.y += vb.y; a1.z += vb.z; a1.w += vb.w;
    }
    if (e < s1) {
        float4 va = *(const float4*)&x[(size_t)esrc[e] * 64 + l4];
        a0.x += va.x; a0.y += va.y; a0.z += va.z; a0.w += va.w;
    }
    a0.x += a1.x; a0.y += a1.y; a0.z += a1.z; a0.w += a1.w;

    a0.x += __shfl_xor(a0.x, 32); a0.y += __shfl_xor(a0.y, 32);
    a0.z += __shfl_xor(a0.z, 32); a0.w += __shfl_xor(a0.w, 32);
    a0.x += __shfl_xor(a0.x, 16); a0.y += __shfl_xor(a0.y, 16);
    a0.z += __shfl_xor(a0.z, 16); a0.w += __shfl_xor(a0.w, 16);

    if (g == 0) {
        float inv = 1.0f / fmaxf((float)(s1 - s0), 1.0f);
        float4 r = make_float4(a0.x * inv, a0.y * inv, a0.z * inv, a0.w * inv);
        *(float4*)&mean[(size_t)node * 64 + l4] = r;
    }
}

// ---------------- MLP + LayerNorm + ELU (lane = node) ----------------
// Block = 64 threads = ONE wave, 64 nodes. Per thread: its node's 128 inputs
// in VGPRs (constant-indexed only -> registers). Weights read with UNIFORM
// addresses -> s_load; v_fmac uses the single allowed SGPR operand -> weights
// cost 0 VGPRs. 8 partial accumulators break the fmac dep chain. h rows go to
// LDS (stride 65 -> 2-way bank alias = free); LN stats accumulated on the fly;
// epilogue does an LDS transpose so global stores are coalesced float4.
// `mean` aliases d_out: this wave reads rows [nbase, nbase+64) at the start
// and writes exactly those rows at the end — no cross-block hazard.
__global__ __launch_bounds__(64) void mlp_kernel(
    const float* x,
    const float* mean,
    const float* __restrict__ Wl,
    const float* __restrict__ Wr,
    const float* __restrict__ bias,
    const float* __restrict__ gamma,
    const float* __restrict__ beta,
    float* out,
    int N)
{
    __shared__ float hbuf[64][65];
    __shared__ float smu[64];
    __shared__ float srs[64];

    int l     = threadIdx.x;        // 0..63, block = one wave
    int nbase = blockIdx.x * 64;
    int node  = nbase + l;
    bool act  = node < N;

    float vm[64], vx[64];
    #pragma unroll
    for (int c = 0; c < 16; ++c) {
        float4 a = act ? *(const float4*)&mean[(size_t)node * 64 + c * 4]
                       : make_float4(0.f, 0.f, 0.f, 0.f);
        float4 b = act ? *(const float4*)&x[(size_t)node * 64 + c * 4]
                       : make_float4(0.f, 0.f, 0.f, 0.f);
        vm[c*4+0] = a.x; vm[c*4+1] = a.y; vm[c*4+2] = a.z; vm[c*4+3] = a.w;
        vx[c*4+0] = b.x; vx[c*4+1] = b.y; vx[c*4+2] = b.z; vx[c*4+3] = b.w;
    }

    float s = 0.f, s2 = 0.f;
    for (int j = 0; j < 64; ++j) {
        const float* wl = Wl + j * 64;   // uniform address -> s_load
        const float* wr = Wr + j * 64;
        float a0 = 0.f, a1 = 0.f, a2 = 0.f, a3 = 0.f;
        float b0 = 0.f, b1 = 0.f, b2 = 0.f, b3 = 0.f;
        #pragma unroll
        for (int d = 0; d < 16; ++d) {
            a0 += wl[d]      * vm[d];
            a1 += wl[d + 16] * vm[d + 16];
            a2 += wl[d + 32] * vm[d + 32];
            a3 += wl[d + 48] * vm[d + 48];
            b0 += wr[d]      * vx[d];
            b1 += wr[d + 16] * vx[d + 16];
            b2 += wr[d + 32] * vx[d + 32];
            b3 += wr[d + 48] * vx[d + 48];
        }
        float hj = bias[j] + ((a0 + a1) + (a2 + a3)) + ((b0 + b1) + (b2 + b3));
        hbuf[l][j] = hj;                 // banks (l+j)%32 -> 2-way, free
        s  += hj;
        s2 += hj * hj;
    }

    float mu  = s * (1.0f / 64.0f);
    float var = s2 * (1.0f / 64.0f) - mu * mu;
    smu[l] = mu;
    srs[l] = rsqrtf(var + LN_EPS);
    // block = one wave: same-wave LDS write->read, no barrier needed

    int j0 = (l & 15) * 4;
    float4 g4 = *(const float4*)&gamma[j0];
    float4 b4 = *(const float4*)&beta[j0];

    #pragma unroll
    for (int c = 0; c < 16; ++c) {
        int n = c * 4 + (l >> 4);       // row within this wave's 64 nodes
        if (nbase + n >= N) break;      // n monotonic in c
        // scalar LDS reads (stride-65 float4 would be misaligned for ds_read_b128)
        float h0 = hbuf[n][j0 + 0];
        float h1 = hbuf[n][j0 + 1];
        float h2 = hbuf[n][j0 + 2];
        float h3 = hbuf[n][j0 + 3];
        float m  = smu[n];
        float r  = srs[n];
        float4 o;
        o.x = (h0 - m) * r * g4.x + b4.x;
        o.y = (h1 - m) * r * g4.y + b4.y;
        o.z = (h2 - m) * r * g4.z + b4.z;
        o.w = (h3 - m) * r * g4.w + b4.w;
        o.x = o.x > 0.f ? o.x : expm1f(o.x);
        o.y = o.y > 0.f ? o.y : expm1f(o.y);
        o.z = o.z > 0.f ? o.z : expm1f(o.z);
        o.w = o.w > 0.f ? o.w : expm1f(o.w);
        *(float4*)&out[(size_t)(nbase + n) * 64 + j0] = o;  // coalesced 1KB/wave
    }
}

extern "C" void kernel_launch(void* const* d_in, const int* in_sizes, int n_in,
                              void* d_out, int out_size, void* d_ws, size_t ws_size,
                              hipStream_t stream) {
    const float* x     = (const float*)d_in[0];
    const int*   ei    = (const int*)  d_in[1];
    const float* Wl    = (const float*)d_in[2];
    const float* Wr    = (const float*)d_in[3];
    const float* bias  = (const float*)d_in[4];
    const float* gamma = (const float*)d_in[5];
    const float* beta  = (const float*)d_in[6];

    int N = in_sizes[0] / 64;
    int E = in_sizes[1] / 2;

    int* deg      = (int*)d_ws;            // N
    int* cursor   = deg + N;               // N
    int* rowstart = cursor + N;            // N+1
    int* tilesum  = rowstart + (N + 1);    // <=64
    int* esrc     = tilesum + 64;          // E
    float* mean   = (float*)d_out;         // N*64; mlp reads its own rows first

    hipMemsetAsync(deg, 0, (size_t)2 * N * sizeof(int), stream);

    int eblocks = (E + 255) / 256;
    hist_kernel<<<eblocks, 256, 0, stream>>>(ei, deg, E);

    int T = (N + 2047) / 2048;
    scan1_kernel<<<T, 256, 0, stream>>>(deg, rowstart, tilesum, N);
    scan2_kernel<<<1, 64, 0, stream>>>(tilesum, T);
    scan3_kernel<<<(N + 255) / 256, 256, 0, stream>>>(rowstart, tilesum, N, E);

    fill_kernel<<<eblocks, 256, 0, stream>>>(ei, rowstart, cursor, esrc, E);

    gather_kernel<<<(N + 3) / 4, 256, 0, stream>>>(x, rowstart, esrc, mean, N);

    mlp_kernel<<<(N + 63) / 64, 64, 0, stream>>>(x, mean, Wl, Wr, bias, gamma, beta,
                                                 (float*)d_out, N);
}

// Round 6
// 228.381 us; speedup vs baseline: 4.7460x; 1.1891x over previous
//
#include <hip/hip_runtime.h>
#include <hip/hip_bf16.h>

#define LN_EPS 1e-5f

// ---------------- CSR build ----------------

__global__ __launch_bounds__(256) void hist_kernel(
    const int* __restrict__ ei, int* __restrict__ deg, int E)
{
    int e = blockIdx.x * 256 + threadIdx.x;
    if (e < E) atomicAdd(&deg[ei[E + e]], 1);
}

__global__ __launch_bounds__(256) void scan1_kernel(
    const int* __restrict__ deg, int* __restrict__ rowstart,
    int* __restrict__ tilesum, int n)
{
    __shared__ int wsum[4];
    int t = threadIdx.x;
    int base = blockIdx.x * 2048 + t * 8;
    int v[8]; int tsum = 0;
    #pragma unroll
    for (int i = 0; i < 8; ++i) { v[i] = (base + i < n) ? deg[base + i] : 0; tsum += v[i]; }
    int lane = t & 63, w = t >> 6;
    int sc = tsum;
    #pragma unroll
    for (int off = 1; off < 64; off <<= 1) {
        int y = __shfl_up(sc, off);
        if (lane >= off) sc += y;
    }
    if (lane == 63) wsum[w] = sc;
    __syncthreads();
    int woff = 0;
    for (int j = 0; j < w; ++j) woff += wsum[j];
    int run = woff + sc - tsum;
    #pragma unroll
    for (int i = 0; i < 8; ++i) { if (base + i < n) rowstart[base + i] = run; run += v[i]; }
    if (t == 255) tilesum[blockIdx.x] = wsum[0] + wsum[1] + wsum[2] + wsum[3];
}

__global__ void scan2_kernel(int* tilesum, int T)
{
    if (blockIdx.x == 0 && threadIdx.x == 0) {
        int run = 0;
        for (int i = 0; i < T; ++i) { int v = tilesum[i]; tilesum[i] = run; run += v; }
    }
}

__global__ __launch_bounds__(256) void scan3_kernel(
    int* __restrict__ rowstart, const int* __restrict__ tilesum, int n, int E)
{
    int i = blockIdx.x * 256 + threadIdx.x;
    if (i < n) rowstart[i] += tilesum[i >> 11];
    if (i == 0) rowstart[n] = E;
}

__global__ __launch_bounds__(256) void fill_kernel(
    const int* __restrict__ ei, const int* __restrict__ rowstart,
    int* __restrict__ cursor, int* __restrict__ esrc, int E)
{
    int e = blockIdx.x * 256 + threadIdx.x;
    if (e < E) {
        int dst = ei[E + e];
        int pos = rowstart[dst] + atomicAdd(&cursor[dst], 1);
        esrc[pos] = ei[e];
    }
}

// ---------------- gather: CSR mean-aggregate (round-3 proven) ----------------
// One node per wave; wave = 4 edge-groups x 16 lanes x float4 (256B/row).
// 8 loads in flight per wave, 100k-wave TLP hides latency. No LDS, low VGPR.
__global__ __launch_bounds__(256) void gather_kernel(
    const float* __restrict__ x,
    const int*   __restrict__ rowstart,
    const int*   __restrict__ esrc,
    float* __restrict__ mean,
    int N)
{
    int tid  = threadIdx.x;
    int lane = tid & 63;
    int g    = lane >> 4;
    int l4   = (lane & 15) * 4;
    int node = blockIdx.x * 4 + (tid >> 6);
    if (node >= N) return;
    int s0 = rowstart[node], s1 = rowstart[node + 1];

    float4 a0 = make_float4(0.f, 0.f, 0.f, 0.f);
    float4 a1 = make_float4(0.f, 0.f, 0.f, 0.f);
    int e = s0 + g;
    for (; e + 4 < s1; e += 8) {
        int sA = esrc[e];
        int sB = esrc[e + 4];
        float4 va = *(const float4*)&x[(size_t)sA * 64 + l4];
        float4 vb = *(const float4*)&x[(size_t)sB * 64 + l4];
        a0.x += va.x; a0.y += va.y; a0.z += va.z; a0.w += va.w;
        a1.x += vb.x; a1.y += vb.y; a1.z += vb.z; a1.w += vb.w;
    }
    if (e < s1) {
        float4 va = *(const float4*)&x[(size_t)esrc[e] * 64 + l4];
        a0.x += va.x; a0.y += va.y; a0.z += va.z; a0.w += va.w;
    }
    a0.x += a1.x; a0.y += a1.y; a0.z += a1.z; a0.w += a1.w;

    a0.x += __shfl_xor(a0.x, 32); a0.y += __shfl_xor(a0.y, 32);
    a0.z += __shfl_xor(a0.z, 32); a0.w += __shfl_xor(a0.w, 32);
    a0.x += __shfl_xor(a0.x, 16); a0.y += __shfl_xor(a0.y, 16);
    a0.z += __shfl_xor(a0.z, 16); a0.w += __shfl_xor(a0.w, 16);

    if (g == 0) {
        float inv = 1.0f / fmaxf((float)(s1 - s0), 1.0f);
        float4 r = make_float4(a0.x * inv, a0.y * inv, a0.z * inv, a0.w * inv);
        *(float4*)&mean[(size_t)node * 64 + l4] = r;
    }
}

// ---------------- MLP + LayerNorm + ELU (thread = node, acc-resident) ----------------
// Thread = node; acc[64] = the node's full output row, lives in VGPRs for the
// whole kernel (accumulators are not rematerializable -> compiler CANNOT demote
// them, unlike round-5's input-resident layout which got remat'ed into the
// loop). Inputs stream through 8-float chunks (short-lived regs, constant-
// indexed). Weight addresses are wave-uniform -> s_load; v_fmac uses its one
// SGPR operand -> weights occupy zero VGPRs. No LDS, no cross-lane ops; LN is
// an in-thread register reduction; each thread stores its own row (16 float4).
// `mean` aliases `out`: each thread reads exactly the row it later writes.
__global__ __launch_bounds__(64, 1) void mlp_kernel(
    const float* __restrict__ x,
    const float* mean,              // aliases out - no restrict
    const float* __restrict__ Wl,
    const float* __restrict__ Wr,
    const float* __restrict__ bias,
    const float* __restrict__ gamma,
    const float* __restrict__ beta,
    float* out,
    int N)
{
    int node = blockIdx.x * 64 + threadIdx.x;
    bool act = node < N;
    size_t row = (size_t)(act ? node : 0) * 64;

    float acc[64];
    #pragma unroll
    for (int j = 0; j < 64; ++j) acc[j] = bias[j];   // uniform -> s_load

    for (int c = 0; c < 8; ++c) {                    // rolled: streams inputs
        float4 ma = *(const float4*)&mean[row + c * 8];
        float4 mb = *(const float4*)&mean[row + c * 8 + 4];
        float4 xa = *(const float4*)&x[row + c * 8];
        float4 xb = *(const float4*)&x[row + c * 8 + 4];
        float vm[8] = {ma.x, ma.y, ma.z, ma.w, mb.x, mb.y, mb.z, mb.w};
        float vx[8] = {xa.x, xa.y, xa.z, xa.w, xb.x, xb.y, xb.z, xb.w};
        const float* wlc = Wl + c * 8;               // uniform base
        const float* wrc = Wr + c * 8;
        #pragma unroll
        for (int j = 0; j < 64; ++j) {
            #pragma unroll
            for (int d = 0; d < 8; ++d) {
                acc[j] += wlc[j * 64 + d] * vm[d]    // s_w * v_in -> v_fmac
                        + wrc[j * 64 + d] * vx[d];
            }
        }
    }

    // LayerNorm stats: pure in-thread reduction (4 partials to shorten chain)
    float s0 = 0.f, s1 = 0.f, q0 = 0.f, q1 = 0.f;
    #pragma unroll
    for (int j = 0; j < 32; ++j) {
        s0 += acc[j];      q0 += acc[j] * acc[j];
        s1 += acc[j + 32]; q1 += acc[j + 32] * acc[j + 32];
    }
    float mu  = (s0 + s1) * (1.0f / 64.0f);
    float var = (q0 + q1) * (1.0f / 64.0f) - mu * mu;
    float r   = rsqrtf(var + LN_EPS);

    if (act) {
        #pragma unroll
        for (int c = 0; c < 16; ++c) {
            float4 g4 = *(const float4*)&gamma[c * 4];   // uniform -> s_load
            float4 b4 = *(const float4*)&beta[c * 4];
            float4 o;
            o.x = (acc[c*4+0] - mu) * r * g4.x + b4.x;
            o.y = (acc[c*4+1] - mu) * r * g4.y + b4.y;
            o.z = (acc[c*4+2] - mu) * r * g4.z + b4.z;
            o.w = (acc[c*4+3] - mu) * r * g4.w + b4.w;
            o.x = o.x > 0.f ? o.x : __expf(o.x) - 1.0f;  // ELU via fast exp
            o.y = o.y > 0.f ? o.y : __expf(o.y) - 1.0f;
            o.z = o.z > 0.f ? o.z : __expf(o.z) - 1.0f;
            o.w = o.w > 0.f ? o.w : __expf(o.w) - 1.0f;
            *(float4*)&out[(size_t)node * 64 + c * 4] = o;
        }
    }
}

extern "C" void kernel_launch(void* const* d_in, const int* in_sizes, int n_in,
                              void* d_out, int out_size, void* d_ws, size_t ws_size,
                              hipStream_t stream) {
    const float* x     = (const float*)d_in[0];
    const int*   ei    = (const int*)  d_in[1];
    const float* Wl    = (const float*)d_in[2];
    const float* Wr    = (const float*)d_in[3];
    const float* bias  = (const float*)d_in[4];
    const float* gamma = (const float*)d_in[5];
    const float* beta  = (const float*)d_in[6];

    int N = in_sizes[0] / 64;
    int E = in_sizes[1] / 2;

    int* deg      = (int*)d_ws;            // N
    int* cursor   = deg + N;               // N
    int* rowstart = cursor + N;            // N+1
    int* tilesum  = rowstart + (N + 1);    // <=64
    int* esrc     = tilesum + 64;          // E
    float* mean   = (float*)d_out;         // N*64; mlp reads its own row first

    hipMemsetAsync(deg, 0, (size_t)2 * N * sizeof(int), stream);

    int eblocks = (E + 255) / 256;
    hist_kernel<<<eblocks, 256, 0, stream>>>(ei, deg, E);

    int T = (N + 2047) / 2048;
    scan1_kernel<<<T, 256, 0, stream>>>(deg, rowstart, tilesum, N);
    scan2_kernel<<<1, 64, 0, stream>>>(tilesum, T);
    scan3_kernel<<<(N + 255) / 256, 256, 0, stream>>>(rowstart, tilesum, N, E);

    fill_kernel<<<eblocks, 256, 0, stream>>>(ei, rowstart, cursor, esrc, E);

    gather_kernel<<<(N + 3) / 4, 256, 0, stream>>>(x, rowstart, esrc, mean, N);

    mlp_kernel<<<(N + 63) / 64, 64, 0, stream>>>(x, mean, Wl, Wr, bias, gamma, beta,
                                                 (float*)d_out, N);
}